// Round 4
// baseline (430.207 us; speedup 1.0000x reference)
//
#include <hip/hip_runtime.h>
#include <math.h>

typedef float f32x4 __attribute__((ext_vector_type(4)));
typedef short s16x8 __attribute__((ext_vector_type(8)));

#define L2E 1.4426950408889634f
#define C2L2E 2.885390081777927f  // 2*log2(e)

// ---------------- K0: W -> bf16 hi/lo, slice-major [kstep][e][k32] ----------
// XOR-swizzled within each 64B row: kl ^= ((e>>1)&3)<<3, so kA's ds_read_b128
// start-banks spread over 8 groups (same conflict profile as the r0 layout).
// Layout + swizzle verified numerically in round 2 (passed; slowdown there was
// register spill from a bad launch_bounds cap, not this layout).
__global__ void k0_prep(const float* __restrict__ W,
                        unsigned short* __restrict__ gWhi,
                        unsigned short* __restrict__ gWlo,
                        float* __restrict__ S) {
  int bid = blockIdx.x;
  if (bid < 64) {
    int t = bid * 256 + threadIdx.x;  // 0..16383
    int d = t >> 7, e = t & 127;      // d = contraction index, e = out feature
    float w = W[d * 128 + e];
    unsigned u = __float_as_uint(w);
    unsigned hb = (u + 0x7fffu + ((u >> 16) & 1u)) >> 16;  // RNE hi
    float r = w - __uint_as_float(hb << 16);
    unsigned ul = __float_as_uint(r);
    unsigned lb = (ul + 0x7fffu + ((ul >> 16) & 1u)) >> 16;  // RNE lo
    int s = d >> 5, kl = d & 31;
    int addr = s * 4096 + e * 32 + (kl ^ (((e >> 1) & 3) << 3));
    gWhi[addr] = (unsigned short)hb;
    gWlo[addr] = (unsigned short)lb;
  } else {
    S[(bid - 64) * 256 + threadIdx.x] = 0.f;  // 4096 row-sum slots
  }
}

// ---------------- KA: E=exp(logit) + row sums, triangular + mirror ----------
// 512 threads = 8 waves; each wave owns 2 i-rows x 16 j x 128 e (r3 decomp,
// acc = 64 AGPR). W staged per-kstep (16KB hi+lo slices), double-buffered:
// T14 split (prefetch global->reg early, ds_write after MFMA, one barrier per
// kstep). LDS ~41.3KB -> 3 blocks/CU = 6 waves/SIMD (vs r3's 2 blocks / 4).
// launch_bounds(512,6): VGPR cap ~341 >> ~150 used -> no spill (r2 lesson).
__global__ __launch_bounds__(512, 6) void kA_logits(
    const float* __restrict__ x, const unsigned short* __restrict__ gWhi,
    const unsigned short* __restrict__ gWlo, const float* __restrict__ apb,
    const float* __restrict__ av, float* __restrict__ Lg,
    float* __restrict__ S) {
  __shared__ __align__(16) unsigned short sWhi[2][4096];
  __shared__ __align__(16) unsigned short sWlo[2][4096];
  __shared__ __align__(16) float sXj[16 * 132];
  __shared__ float sRow[16][8];
  __shared__ float sMir[16];

  int tt = blockIdx.x, ti = 0;
  while (tt >= 16 - ti) { tt -= 16 - ti; ++ti; }
  const int tj = ti + tt;
  const int b = blockIdx.y;
  const int i0 = ti * 16, j0 = tj * 16;
  const int tid = threadIdx.x;

  {  // prologue: stage W slice 0 (hi+lo, 1 uint4 each/thread) + x_j rows
    ((uint4*)sWhi[0])[tid] = ((const uint4*)gWhi)[tid];
    ((uint4*)sWlo[0])[tid] = ((const uint4*)gWlo)[tid];
    const float4* xsrc = (const float4*)(x + ((size_t)(b * 256 + j0)) * 128);
    *(float4*)&sXj[(tid >> 5) * 132 + (tid & 31) * 4] = xsrc[tid];
  }
  __syncthreads();

  const int lane = tid & 63;
  const int w = tid >> 6;  // 0..7
  const int quad = lane >> 4;
  const int col = lane & 15;
  const int xsw = ((col >> 1) & 3) << 3;  // == ((e>>1)&3)<<3 since e=col+16et

  float vw[8];
  f32x4 acc[2][8];
#pragma unroll
  for (int et = 0; et < 8; ++et) {
    float bi = apb[col + 16 * et];
    vw[et] = av[col + 16 * et];
#pragma unroll
    for (int mt = 0; mt < 2; ++mt) acc[mt][et] = (f32x4){bi, bi, bi, bi};
  }

  const float* xib = x + ((size_t)(b * 256 + i0 + 2 * w)) * 128;

#pragma unroll
  for (int kstep = 0; kstep < 4; ++kstep) {
    const int cb = kstep & 1;
    // T14 issue-early: next W slice global->reg (16 VGPRs in flight)
    uint4 rh, rl;
    if (kstep < 3) {
      rh = ((const uint4*)(gWhi + (kstep + 1) * 4096))[tid];
      rl = ((const uint4*)(gWlo + (kstep + 1) * 4096))[tid];
    }

    const int k0 = kstep * 32 + quad * 8;
    float4 xj0 = *(const float4*)&sXj[col * 132 + k0];
    float4 xj1 = *(const float4*)&sXj[col * 132 + k0 + 4];
    s16x8 Ah[2], Al[2];
#pragma unroll
    for (int mt = 0; mt < 2; ++mt) {
      const float* xip = xib + mt * 128 + k0;
      float4 xi0 = *(const float4*)xip;
      float4 xi1 = *(const float4*)(xip + 4);
      float pv[8];
      pv[0] = xi0.x * xj0.x; pv[1] = xi0.y * xj0.y;
      pv[2] = xi0.z * xj0.z; pv[3] = xi0.w * xj0.w;
      pv[4] = xi1.x * xj1.x; pv[5] = xi1.y * xj1.y;
      pv[6] = xi1.z * xj1.z; pv[7] = xi1.w * xj1.w;
      uint4 hp, lp;
      unsigned* hq = (unsigned*)&hp;
      unsigned* lq = (unsigned*)&lp;
#pragma unroll
      for (int p = 0; p < 4; ++p) {
        unsigned u0 = __float_as_uint(pv[2 * p]);
        unsigned u1 = __float_as_uint(pv[2 * p + 1]);
        hq[p] = __builtin_amdgcn_perm(u1, u0, 0x07060302);
        float h0 = __uint_as_float(u0 & 0xffff0000u);
        float h1 = __uint_as_float(u1 & 0xffff0000u);
        unsigned v0 = __float_as_uint(pv[2 * p] - h0) + 0x8000u;
        unsigned v1 = __float_as_uint(pv[2 * p + 1] - h1) + 0x8000u;
        lq[p] = __builtin_amdgcn_perm(v1, v0, 0x07060302);
      }
      Ah[mt] = *(s16x8*)&hp;
      Al[mt] = *(s16x8*)&lp;
    }
    const int kq = (quad * 8) ^ xsw;
#pragma unroll
    for (int et = 0; et < 8; ++et) {
      const int addr = (col + 16 * et) * 32 + kq;
      s16x8 bh = *(const s16x8*)&sWhi[cb][addr];
      s16x8 bl = *(const s16x8*)&sWlo[cb][addr];
#pragma unroll
      for (int mt = 0; mt < 2; ++mt) {
        acc[mt][et] = __builtin_amdgcn_mfma_f32_16x16x32_bf16(Ah[mt], bh, acc[mt][et], 0, 0, 0);
        acc[mt][et] = __builtin_amdgcn_mfma_f32_16x16x32_bf16(Al[mt], bh, acc[mt][et], 0, 0, 0);
        acc[mt][et] = __builtin_amdgcn_mfma_f32_16x16x32_bf16(Ah[mt], bl, acc[mt][et], 0, 0, 0);
      }
    }
    // T14 write-late: commit next slice to the other buffer, then one barrier.
    // Safe: buf cb^1 was last READ in kstep-1, whose trailing barrier has
    // already passed; buf cb for kstep+1... written here before the barrier.
    if (kstep < 3) {
      const int nb = cb ^ 1;
      ((uint4*)sWhi[nb])[tid] = rh;
      ((uint4*)sWlo[nb])[tid] = rl;
      __syncthreads();
    }
  }

  // epilogue: logit -> E = exp(logit) (no max-sub; |logit|<~8 so safe)
  float E[2];
#pragma unroll
  for (int mt = 0; mt < 2; ++mt) {
    float ls[4] = {0.f, 0.f, 0.f, 0.f};
#pragma unroll
    for (int et = 0; et < 8; ++et) {
#pragma unroll
      for (int r = 0; r < 4; ++r) {
        float e2 = __builtin_amdgcn_exp2f(acc[mt][et][r] * C2L2E);
        float t = 1.0f - 2.0f * __builtin_amdgcn_rcpf(e2 + 1.0f);
        ls[r] += t * vw[et];
      }
    }
#pragma unroll
    for (int m = 1; m < 16; m <<= 1) {
      ls[0] += __shfl_xor(ls[0], m);
      ls[1] += __shfl_xor(ls[1], m);
      ls[2] += __shfl_xor(ls[2], m);
      ls[3] += __shfl_xor(ls[3], m);
    }
    float fl = (col == 0) ? ls[0] : (col == 1) ? ls[1] : (col == 2) ? ls[2] : ls[3];
    E[mt] = __builtin_amdgcn_exp2f(fl * L2E);
  }

  if (col < 4) {  // primary tile write (E for rows j in tj-tile, cols i in ti)
    const int j = j0 + quad * 4 + col;
    float2 val = {E[0], E[1]};
    *(float2*)&Lg[((size_t)(b * 256 + j)) * 256 + i0 + 2 * w] = val;
    sRow[quad * 4 + col][w] = E[0] + E[1];
  }

  if (ti != tj) {  // mirror write + mirror row sums
    if (col < 4) {
      const int j = j0 + quad * 4 + col;
#pragma unroll
      for (int mt = 0; mt < 2; ++mt)
        Lg[((size_t)(b * 256 + i0 + 2 * w + mt)) * 256 + j] = E[mt];
    }
#pragma unroll
    for (int mt = 0; mt < 2; ++mt) {
      float v = (col < 4) ? E[mt] : 0.f;
#pragma unroll
      for (int m = 1; m < 64; m <<= 1) v += __shfl_xor(v, m);
      if (lane == 0) sMir[2 * w + mt] = v;
    }
  }
  __syncthreads();
  if (tid < 16) {
    float rs = sRow[tid][0];
#pragma unroll
    for (int q = 1; q < 8; ++q) rs += sRow[tid][q];
    atomicAdd(&S[b * 256 + j0 + tid], rs);
    if (ti != tj) atomicAdd(&S[b * 256 + i0 + tid], sMir[tid]);
  }
}

// ---------------- KB: agg (att=E/S) + h (fp64) + pool scores ----------------
__global__ void kB_aggh(const float* __restrict__ Lg, const float* __restrict__ S,
                        const float* __restrict__ x,
                        const float* __restrict__ pwa, const float* __restrict__ pwoa,
                        const float* __restrict__ pwab, const float* __restrict__ pwob,
                        const float* __restrict__ gam, const float* __restrict__ bet,
                        const float* __restrict__ mea, const float* __restrict__ varr,
                        const float* __restrict__ plw, const float* __restrict__ plb,
                        float* __restrict__ h, float* __restrict__ scores) {
  const int b = blockIdx.y, i0 = blockIdx.x * 8;
  const int tid = threadIdx.x;
  const int il = tid >> 5, dl = tid & 31;  // 8 i x 32 d-chunks
  __shared__ float sInv[256];
  __shared__ float satt[16][8];
  __shared__ float sxj[2048];
  __shared__ float sa[1024];
  __shared__ float sxi[1024];
  __shared__ double sScD[8][32];

  sInv[tid] = 1.0f / S[b * 256 + tid];
  ((float4*)sxi)[tid] = ((const float4*)(x + ((size_t)(b * 256 + i0)) * 128))[tid];

  float acc[4] = {0.f, 0.f, 0.f, 0.f};
  for (int jj = 0; jj < 256; jj += 16) {
    __syncthreads();
    if (tid < 128)
      satt[tid >> 3][tid & 7] =
          Lg[((size_t)(b * 256 + jj + (tid >> 3))) * 256 + i0 + (tid & 7)] *
          sInv[jj + (tid >> 3)];
    const float4* xsrc = (const float4*)(x + ((size_t)(b * 256 + jj)) * 128);
    ((float4*)sxj)[tid] = xsrc[tid];
    ((float4*)sxj)[tid + 256] = xsrc[tid + 256];
    __syncthreads();
#pragma unroll
    for (int jl = 0; jl < 16; ++jl) {
      float a = satt[jl][il];
      float4 xv = *(const float4*)&sxj[jl * 128 + dl * 4];
      acc[0] += a * xv.x; acc[1] += a * xv.y;
      acc[2] += a * xv.z; acc[3] += a * xv.w;
    }
  }
  __syncthreads();
  *(float4*)&sa[il * 128 + dl * 4] = *(float4*)acc;
  __syncthreads();

  double z[4] = {0, 0, 0, 0};
  for (int k = 0; k < 128; ++k) {
    double a = (double)sa[il * 128 + k];
    float4 wv = *(const float4*)(pwa + k * 128 + dl * 4);
    z[0] += a * (double)wv.x; z[1] += a * (double)wv.y;
    z[2] += a * (double)wv.z; z[3] += a * (double)wv.w;
  }
  for (int k = 0; k < 128; ++k) {
    double a = (double)sxi[il * 128 + k];
    float4 wv = *(const float4*)(pwoa + k * 128 + dl * 4);
    z[0] += a * (double)wv.x; z[1] += a * (double)wv.y;
    z[2] += a * (double)wv.z; z[3] += a * (double)wv.w;
  }
  float o[4];
#pragma unroll
  for (int q = 0; q < 4; ++q) {
    int d = dl * 4 + q;
    double hv = z[q] + (double)pwab[d] + (double)pwob[d];
    double bn = (hv - (double)mea[d]) * (1.0 / sqrt((double)varr[d] + 1e-5)) *
                    (double)gam[d] +
                (double)bet[d];
    float bf = (float)bn;
    o[q] = bf > 0.f ? 1.0507009873554805f * bf
                    : 1.7580993408473766f *
                          (__builtin_amdgcn_exp2f(bf * L2E) - 1.0f);
  }
  *(float4*)(h + ((size_t)(b * 256 + i0 + il)) * 128 + dl * 4) = *(float4*)o;

  // pool score partials (fp64, fixed reduction order -> deterministic)
  sScD[il][dl] = (double)o[0] * (double)plw[dl * 4] +
                 (double)o[1] * (double)plw[dl * 4 + 1] +
                 (double)o[2] * (double)plw[dl * 4 + 2] +
                 (double)o[3] * (double)plw[dl * 4 + 3];
  __syncthreads();
  if (tid < 8) {
    double zz = (double)plb[0];
    for (int c = 0; c < 32; ++c) zz += sScD[tid][c];
    scores[b * 256 + i0 + tid] = (float)(1.0 / (1.0 + exp(-zz)));
  }
}

// ---------------- KC: stable top-128 rank + gather h*score ------------------
__global__ __launch_bounds__(1024) void kC_topk(const float* __restrict__ h,
                                                const float* __restrict__ scores,
                                                float* __restrict__ out) {
  const int b = blockIdx.x, tid = threadIdx.x;
  const int t = tid >> 2, c = tid & 3;
  __shared__ float sc[256];
  __shared__ int ipart[256][4];
  __shared__ int sel[128];

  if (c == 0) sc[t] = scores[b * 256 + t];
  __syncthreads();
  {
    const float st = sc[t];
    int r = 0;
    for (int m = c * 64; m < c * 64 + 64; ++m) {
      float sm = sc[m];
      r += (sm > st) || (sm == st && m < t);  // stable descending
    }
    ipart[t][c] = r;
  }
  __syncthreads();
  if (c == 0) {
    int rank = ipart[t][0] + ipart[t][1] + ipart[t][2] + ipart[t][3];
    if (rank < 128) sel[rank] = t;
  }
  __syncthreads();
  const float4* h4 = (const float4*)(h + (size_t)b * 256 * 128);
  float4* o4 = (float4*)(out + (size_t)b * 128 * 128);
#pragma unroll
  for (int r = 0; r < 4; ++r) {
    int v = tid + 1024 * r;
    int row = v >> 5, q = v & 31;
    int src = sel[row];
    float ss = sc[src];
    float4 hv = h4[src * 32 + q];
    float4 ov;
    ov.x = hv.x * ss; ov.y = hv.y * ss; ov.z = hv.z * ss; ov.w = hv.w * ss;
    o4[row * 32 + q] = ov;
  }
}

extern "C" void kernel_launch(void* const* d_in, const int* in_sizes, int n_in,
                              void* d_out, int out_size, void* d_ws, size_t ws_size,
                              hipStream_t stream) {
  const float* x    = (const float*)d_in[0];
  const float* apw  = (const float*)d_in[1];
  const float* apb  = (const float*)d_in[2];
  const float* av   = (const float*)d_in[3];
  const float* pwa  = (const float*)d_in[4];
  const float* pwab = (const float*)d_in[5];
  const float* pwoa = (const float*)d_in[6];
  const float* pwob = (const float*)d_in[7];
  const float* gam  = (const float*)d_in[8];
  const float* bet  = (const float*)d_in[9];
  const float* mea  = (const float*)d_in[10];
  const float* varr = (const float*)d_in[11];
  const float* plw  = (const float*)d_in[12];
  const float* plb  = (const float*)d_in[13];
  float* out = (float*)d_out;

  // ws: gWhi 32K | gWlo 32K | S 16K | Lg 4M | h 2M | scores 16K
  unsigned short* gWhi = (unsigned short*)d_ws;
  unsigned short* gWlo = gWhi + 16384;
  float* S  = (float*)((char*)d_ws + 65536);
  float* Lg = (float*)((char*)d_ws + 81920);
  float* hb = Lg + (size_t)16 * 256 * 256;
  float* sco = hb + (size_t)16 * 256 * 128;

  k0_prep<<<80, 256, 0, stream>>>(apw, gWhi, gWlo, S);
  kA_logits<<<dim3(136, 16), 512, 0, stream>>>(x, gWhi, gWlo, apb, av, Lg, S);
  kB_aggh<<<dim3(32, 16), 256, 0, stream>>>(Lg, S, x, pwa, pwoa, pwab, pwob,
                                            gam, bet, mea, varr, plw, plb, hb, sco);
  kC_topk<<<16, 1024, 0, stream>>>(hb, sco, out);
}

// Round 5
// 177.696 us; speedup vs baseline: 2.4210x; 2.4210x over previous
//
#include <hip/hip_runtime.h>
#include <math.h>

typedef float f32x4 __attribute__((ext_vector_type(4)));
typedef short s16x8 __attribute__((ext_vector_type(8)));

#define L2E 1.4426950408889634f
#define C2L2E 2.885390081777927f  // 2*log2(e)

// ---------------- K0: W -> bf16 hi/lo (W^T, XOR-swizzled) + zero S ----------
__global__ void k0_prep(const float* __restrict__ W,
                        unsigned short* __restrict__ gWhi,
                        unsigned short* __restrict__ gWlo,
                        float* __restrict__ S) {
  int bid = blockIdx.x;
  if (bid < 64) {
    int t = bid * 256 + threadIdx.x;  // 0..16383
    int d = t >> 7, e = t & 127;
    float w = W[d * 128 + e];
    unsigned u = __float_as_uint(w);
    unsigned hb = (u + 0x7fffu + ((u >> 16) & 1u)) >> 16;  // RNE hi
    float r = w - __uint_as_float(hb << 16);
    unsigned ul = __float_as_uint(r);
    unsigned lb = (ul + 0x7fffu + ((ul >> 16) & 1u)) >> 16;  // RNE lo
    int addr = e * 128 + (d ^ ((e & 7) << 3));
    gWhi[addr] = (unsigned short)hb;
    gWlo[addr] = (unsigned short)lb;
  } else {
    S[(bid - 64) * 256 + threadIdx.x] = 0.f;  // 4096 row-sum slots
  }
}

// ---------------- KA: E=exp(logit) + row sums, triangular + mirror ----------
// Round-3 verified config: 512 threads = 8 waves, 2 i-rows/wave, acc = 64
// AGPR. Register budget: per-SIMD pool = 512 regs/wave-slot; (512,4) caps at
// 128/wave = 64 VGPR + 64 acc AGPR exactly -> no spill (r4 lesson: (512,6)
// caps at 85 -> catastrophic spill). This decomposition's occupancy ceiling.
__global__ __launch_bounds__(512, 4) void kA_logits(
    const float* __restrict__ x, const unsigned short* __restrict__ gWhi,
    const unsigned short* __restrict__ gWlo, const float* __restrict__ apb,
    const float* __restrict__ av, float* __restrict__ Lg,
    float* __restrict__ S) {
  __shared__ __align__(16) unsigned short sWhi[16384];
  __shared__ __align__(16) unsigned short sWlo[16384];
  __shared__ __align__(16) float sXj[16 * 132];
  __shared__ float sRow[16][8];
  __shared__ float sMir[16];

  int tt = blockIdx.x, ti = 0;
  while (tt >= 16 - ti) { tt -= 16 - ti; ++ti; }
  const int tj = ti + tt;
  const int b = blockIdx.y;
  const int i0 = ti * 16, j0 = tj * 16;
  const int tid = threadIdx.x;

  {  // stage W hi/lo (pre-swizzled copy) + x_j rows
    const uint4* shi = (const uint4*)gWhi;
    const uint4* slo = (const uint4*)gWlo;
    uint4* dhi = (uint4*)sWhi;
    uint4* dlo = (uint4*)sWlo;
#pragma unroll
    for (int r = 0; r < 4; ++r) {
      dhi[tid + 512 * r] = shi[tid + 512 * r];
      dlo[tid + 512 * r] = slo[tid + 512 * r];
    }
    const float4* xsrc = (const float4*)(x + ((size_t)(b * 256 + j0)) * 128);
    *(float4*)&sXj[(tid >> 5) * 132 + (tid & 31) * 4] = xsrc[tid];
  }
  __syncthreads();

  const int lane = tid & 63;
  const int w = tid >> 6;  // 0..7
  const int quad = lane >> 4;
  const int col = lane & 15;
  const int swz = (col & 7) << 3;

  float vw[8];
  f32x4 acc[2][8];
#pragma unroll
  for (int et = 0; et < 8; ++et) {
    float bi = apb[col + 16 * et];
    vw[et] = av[col + 16 * et];
#pragma unroll
    for (int mt = 0; mt < 2; ++mt) acc[mt][et] = (f32x4){bi, bi, bi, bi};
  }

  const float* xib = x + ((size_t)(b * 256 + i0 + 2 * w)) * 128;

#pragma unroll
  for (int kstep = 0; kstep < 4; ++kstep) {
    const int k0 = kstep * 32 + quad * 8;
    float4 xj0 = *(const float4*)&sXj[col * 132 + k0];
    float4 xj1 = *(const float4*)&sXj[col * 132 + k0 + 4];
    s16x8 Ah[2], Al[2];
#pragma unroll
    for (int mt = 0; mt < 2; ++mt) {
      const float* xip = xib + mt * 128 + k0;
      float4 xi0 = *(const float4*)xip;
      float4 xi1 = *(const float4*)(xip + 4);
      float pv[8];
      pv[0] = xi0.x * xj0.x; pv[1] = xi0.y * xj0.y;
      pv[2] = xi0.z * xj0.z; pv[3] = xi0.w * xj0.w;
      pv[4] = xi1.x * xj1.x; pv[5] = xi1.y * xj1.y;
      pv[6] = xi1.z * xj1.z; pv[7] = xi1.w * xj1.w;
      uint4 hp, lp;
      unsigned* hq = (unsigned*)&hp;
      unsigned* lq = (unsigned*)&lp;
#pragma unroll
      for (int p = 0; p < 4; ++p) {
        unsigned u0 = __float_as_uint(pv[2 * p]);
        unsigned u1 = __float_as_uint(pv[2 * p + 1]);
        hq[p] = __builtin_amdgcn_perm(u1, u0, 0x07060302);
        float h0 = __uint_as_float(u0 & 0xffff0000u);
        float h1 = __uint_as_float(u1 & 0xffff0000u);
        unsigned v0 = __float_as_uint(pv[2 * p] - h0) + 0x8000u;
        unsigned v1 = __float_as_uint(pv[2 * p + 1] - h1) + 0x8000u;
        lq[p] = __builtin_amdgcn_perm(v1, v0, 0x07060302);
      }
      Ah[mt] = *(s16x8*)&hp;
      Al[mt] = *(s16x8*)&lp;
    }
#pragma unroll
    for (int et = 0; et < 8; ++et) {
      const int addr = (col + 16 * et) * 128 + (k0 ^ swz);
      s16x8 bh = *(const s16x8*)&sWhi[addr];
      s16x8 bl = *(const s16x8*)&sWlo[addr];
#pragma unroll
      for (int mt = 0; mt < 2; ++mt) {
        acc[mt][et] = __builtin_amdgcn_mfma_f32_16x16x32_bf16(Ah[mt], bh, acc[mt][et], 0, 0, 0);
        acc[mt][et] = __builtin_amdgcn_mfma_f32_16x16x32_bf16(Al[mt], bh, acc[mt][et], 0, 0, 0);
        acc[mt][et] = __builtin_amdgcn_mfma_f32_16x16x32_bf16(Ah[mt], bl, acc[mt][et], 0, 0, 0);
      }
    }
  }

  // epilogue: logit -> E = exp(logit) (no max-sub; |logit|<~8 so safe)
  float E[2];
#pragma unroll
  for (int mt = 0; mt < 2; ++mt) {
    float ls[4] = {0.f, 0.f, 0.f, 0.f};
#pragma unroll
    for (int et = 0; et < 8; ++et) {
#pragma unroll
      for (int r = 0; r < 4; ++r) {
        float e2 = __builtin_amdgcn_exp2f(acc[mt][et][r] * C2L2E);
        float t = 1.0f - 2.0f * __builtin_amdgcn_rcpf(e2 + 1.0f);
        ls[r] += t * vw[et];
      }
    }
#pragma unroll
    for (int m = 1; m < 16; m <<= 1) {
      ls[0] += __shfl_xor(ls[0], m);
      ls[1] += __shfl_xor(ls[1], m);
      ls[2] += __shfl_xor(ls[2], m);
      ls[3] += __shfl_xor(ls[3], m);
    }
    float fl = (col == 0) ? ls[0] : (col == 1) ? ls[1] : (col == 2) ? ls[2] : ls[3];
    E[mt] = __builtin_amdgcn_exp2f(fl * L2E);
  }

  if (col < 4) {  // primary tile write (E for rows j in tj-tile, cols i in ti)
    const int j = j0 + quad * 4 + col;
    float2 val = {E[0], E[1]};
    *(float2*)&Lg[((size_t)(b * 256 + j)) * 256 + i0 + 2 * w] = val;
    sRow[quad * 4 + col][w] = E[0] + E[1];
  }

  if (ti != tj) {  // mirror write + mirror row sums
    if (col < 4) {
      const int j = j0 + quad * 4 + col;
#pragma unroll
      for (int mt = 0; mt < 2; ++mt)
        Lg[((size_t)(b * 256 + i0 + 2 * w + mt)) * 256 + j] = E[mt];
    }
#pragma unroll
    for (int mt = 0; mt < 2; ++mt) {
      float v = (col < 4) ? E[mt] : 0.f;
#pragma unroll
      for (int m = 1; m < 64; m <<= 1) v += __shfl_xor(v, m);
      if (lane == 0) sMir[2 * w + mt] = v;
    }
  }
  __syncthreads();
  if (tid < 16) {
    float rs = sRow[tid][0];
#pragma unroll
    for (int q = 1; q < 8; ++q) rs += sRow[tid][q];
    atomicAdd(&S[b * 256 + j0 + tid], rs);
    if (ti != tj) atomicAdd(&S[b * 256 + i0 + tid], sMir[tid]);
  }
}

// ---------------- KB: agg (att=E/S) + h (fp64) + pool scores ----------------
// Round-1-verified variant (passed, identical absmax): att rows loaded
// coalesced via Lg symmetry (Lg[i][j] == Lg[j][i] bit-exactly: mirror writes
// + identical MFMA row data), pre-scaled by 1/S once. Removes 16
// barrier-fenced uncoalesced gather phases where half the block idled.
__global__ void kB_aggh(const float* __restrict__ Lg, const float* __restrict__ S,
                        const float* __restrict__ x,
                        const float* __restrict__ pwa, const float* __restrict__ pwoa,
                        const float* __restrict__ pwab, const float* __restrict__ pwob,
                        const float* __restrict__ gam, const float* __restrict__ bet,
                        const float* __restrict__ mea, const float* __restrict__ varr,
                        const float* __restrict__ plw, const float* __restrict__ plb,
                        float* __restrict__ h, float* __restrict__ scores) {
  const int b = blockIdx.y, i0 = blockIdx.x * 8;
  const int tid = threadIdx.x;
  const int il = tid >> 5, dl = tid & 31;  // 8 i x 32 d-chunks
  __shared__ float sInv[256];
  __shared__ float satt[8][256];  // scaled att rows for this block's 8 i's
  __shared__ float sxj[2048];
  __shared__ float sa[1024];
  __shared__ float sxi[1024];
  __shared__ double sScD[8][32];

  sInv[tid] = 1.0f / S[b * 256 + tid];
  ((float4*)sxi)[tid] = ((const float4*)(x + ((size_t)(b * 256 + i0)) * 128))[tid];
  {  // coalesced row loads: att[i][j] = Lg[i][j] * (1/S[j])
    const float4* lsrc = (const float4*)(Lg + ((size_t)(b * 256 + i0)) * 256);
    ((float4*)satt)[tid] = lsrc[tid];
    ((float4*)satt)[tid + 256] = lsrc[tid + 256];
  }
  __syncthreads();
#pragma unroll
  for (int r = 0; r < 8; ++r) {
    int v = tid + 256 * r;  // 0..2047, each element exactly once
    ((float*)satt)[v] *= sInv[v & 255];
  }

  float acc[4] = {0.f, 0.f, 0.f, 0.f};
  for (int jj = 0; jj < 256; jj += 16) {
    __syncthreads();
    const float4* xsrc = (const float4*)(x + ((size_t)(b * 256 + jj)) * 128);
    ((float4*)sxj)[tid] = xsrc[tid];
    ((float4*)sxj)[tid + 256] = xsrc[tid + 256];
    __syncthreads();
#pragma unroll
    for (int jl = 0; jl < 16; ++jl) {
      float a = satt[il][jj + jl];
      float4 xv = *(const float4*)&sxj[jl * 128 + dl * 4];
      acc[0] += a * xv.x; acc[1] += a * xv.y;
      acc[2] += a * xv.z; acc[3] += a * xv.w;
    }
  }
  __syncthreads();
  *(float4*)&sa[il * 128 + dl * 4] = *(float4*)acc;
  __syncthreads();

  double z[4] = {0, 0, 0, 0};
#pragma unroll 8
  for (int k = 0; k < 128; ++k) {
    double a = (double)sa[il * 128 + k];
    float4 wv = *(const float4*)(pwa + k * 128 + dl * 4);
    z[0] += a * (double)wv.x; z[1] += a * (double)wv.y;
    z[2] += a * (double)wv.z; z[3] += a * (double)wv.w;
  }
#pragma unroll 8
  for (int k = 0; k < 128; ++k) {
    double a = (double)sxi[il * 128 + k];
    float4 wv = *(const float4*)(pwoa + k * 128 + dl * 4);
    z[0] += a * (double)wv.x; z[1] += a * (double)wv.y;
    z[2] += a * (double)wv.z; z[3] += a * (double)wv.w;
  }
  float o[4];
#pragma unroll
  for (int q = 0; q < 4; ++q) {
    int d = dl * 4 + q;
    double hv = z[q] + (double)pwab[d] + (double)pwob[d];
    double bn = (hv - (double)mea[d]) * (1.0 / sqrt((double)varr[d] + 1e-5)) *
                    (double)gam[d] +
                (double)bet[d];
    float bf = (float)bn;
    o[q] = bf > 0.f ? 1.0507009873554805f * bf
                    : 1.7580993408473766f *
                          (__builtin_amdgcn_exp2f(bf * L2E) - 1.0f);
  }
  *(float4*)(h + ((size_t)(b * 256 + i0 + il)) * 128 + dl * 4) = *(float4*)o;

  // pool score partials (fp64, fixed reduction order -> deterministic)
  sScD[il][dl] = (double)o[0] * (double)plw[dl * 4] +
                 (double)o[1] * (double)plw[dl * 4 + 1] +
                 (double)o[2] * (double)plw[dl * 4 + 2] +
                 (double)o[3] * (double)plw[dl * 4 + 3];
  __syncthreads();
  if (tid < 8) {
    double zz = (double)plb[0];
    for (int c = 0; c < 32; ++c) zz += sScD[tid][c];
    scores[b * 256 + i0 + tid] = (float)(1.0 / (1.0 + exp(-zz)));
  }
}

// ---------------- KC: stable top-128 rank + gather h*score ------------------
// Round-1-verified variant: 4 blocks per batch (ranks recomputed per block,
// deterministic), each gathers a 32-row quarter -> 4x CU parallelism.
__global__ __launch_bounds__(1024) void kC_topk(const float* __restrict__ h,
                                                const float* __restrict__ scores,
                                                float* __restrict__ out) {
  const int bq = blockIdx.x;
  const int b = bq >> 2, qp = bq & 3;
  const int tid = threadIdx.x;
  const int t = tid >> 2, c = tid & 3;
  __shared__ float sc[256];
  __shared__ int ipart[256][4];
  __shared__ int sel[128];

  if (c == 0) sc[t] = scores[b * 256 + t];
  __syncthreads();
  {
    const float st = sc[t];
    int r = 0;
    for (int m = c * 64; m < c * 64 + 64; ++m) {
      float sm = sc[m];
      r += (sm > st) || (sm == st && m < t);  // stable descending
    }
    ipart[t][c] = r;
  }
  __syncthreads();
  if (c == 0) {
    int rank = ipart[t][0] + ipart[t][1] + ipart[t][2] + ipart[t][3];
    if (rank < 128) sel[rank] = t;
  }
  __syncthreads();
  const float4* h4 = (const float4*)(h + (size_t)b * 256 * 128);
  float4* o4 = (float4*)(out + (size_t)b * 128 * 128);
  const int row = qp * 32 + (tid >> 5);
  const int q = tid & 31;
  int src = sel[row];
  float ss = sc[src];
  float4 hv = h4[src * 32 + q];
  float4 ov;
  ov.x = hv.x * ss; ov.y = hv.y * ss; ov.z = hv.z * ss; ov.w = hv.w * ss;
  o4[row * 32 + q] = ov;
}

extern "C" void kernel_launch(void* const* d_in, const int* in_sizes, int n_in,
                              void* d_out, int out_size, void* d_ws, size_t ws_size,
                              hipStream_t stream) {
  const float* x    = (const float*)d_in[0];
  const float* apw  = (const float*)d_in[1];
  const float* apb  = (const float*)d_in[2];
  const float* av   = (const float*)d_in[3];
  const float* pwa  = (const float*)d_in[4];
  const float* pwab = (const float*)d_in[5];
  const float* pwoa = (const float*)d_in[6];
  const float* pwob = (const float*)d_in[7];
  const float* gam  = (const float*)d_in[8];
  const float* bet  = (const float*)d_in[9];
  const float* mea  = (const float*)d_in[10];
  const float* varr = (const float*)d_in[11];
  const float* plw  = (const float*)d_in[12];
  const float* plb  = (const float*)d_in[13];
  float* out = (float*)d_out;

  // ws: gWhi 32K | gWlo 32K | S 16K | Lg 4M | h 2M | scores 16K
  unsigned short* gWhi = (unsigned short*)d_ws;
  unsigned short* gWlo = gWhi + 16384;
  float* S  = (float*)((char*)d_ws + 65536);
  float* Lg = (float*)((char*)d_ws + 81920);
  float* hb = Lg + (size_t)16 * 256 * 256;
  float* sco = hb + (size_t)16 * 256 * 128;

  k0_prep<<<80, 256, 0, stream>>>(apw, gWhi, gWlo, S);
  kA_logits<<<dim3(136, 16), 512, 0, stream>>>(x, gWhi, gWlo, apb, av, Lg, S);
  kB_aggh<<<dim3(32, 16), 256, 0, stream>>>(Lg, S, x, pwa, pwoa, pwab, pwob,
                                            gam, bet, mea, varr, plw, plb, hb, sco);
  kC_topk<<<64, 1024, 0, stream>>>(hb, sco, out);
}

// Round 6
// 166.988 us; speedup vs baseline: 2.5763x; 1.0641x over previous
//
#include <hip/hip_runtime.h>
#include <math.h>

typedef float f32x4 __attribute__((ext_vector_type(4)));
typedef short s16x8 __attribute__((ext_vector_type(8)));

#define L2E 1.4426950408889634f
#define C2L2E 2.885390081777927f  // 2*log2(e)

// ---------------- K0: W -> bf16 hi/lo (W^T, XOR-swizzled) + zero S ----------
__global__ void k0_prep(const float* __restrict__ W,
                        unsigned short* __restrict__ gWhi,
                        unsigned short* __restrict__ gWlo,
                        float* __restrict__ S) {
  int bid = blockIdx.x;
  if (bid < 64) {
    int t = bid * 256 + threadIdx.x;  // 0..16383
    int d = t >> 7, e = t & 127;
    float w = W[d * 128 + e];
    unsigned u = __float_as_uint(w);
    unsigned hb = (u + 0x7fffu + ((u >> 16) & 1u)) >> 16;  // RNE hi
    float r = w - __uint_as_float(hb << 16);
    unsigned ul = __float_as_uint(r);
    unsigned lb = (ul + 0x7fffu + ((ul >> 16) & 1u)) >> 16;  // RNE lo
    int addr = e * 128 + (d ^ ((e & 7) << 3));
    gWhi[addr] = (unsigned short)hb;
    gWlo[addr] = (unsigned short)lb;
  } else {
    S[(bid - 64) * 256 + threadIdx.x] = 0.f;  // 4096 row-sum slots
  }
}

// ---------------- KA: E=exp(logit) + row sums, triangular + mirror ----------
// Round-3/5 verified config (byte-frozen): 512 threads = 8 waves, 2 i-rows
// per wave, acc = 64 AGPR. Register budget: per-SIMD pool = 512 regs/slot;
// (512,4) caps at 128/wave = 64 VGPR + 64 acc AGPR exactly -> no spill.
__global__ __launch_bounds__(512, 4) void kA_logits(
    const float* __restrict__ x, const unsigned short* __restrict__ gWhi,
    const unsigned short* __restrict__ gWlo, const float* __restrict__ apb,
    const float* __restrict__ av, float* __restrict__ Lg,
    float* __restrict__ S) {
  __shared__ __align__(16) unsigned short sWhi[16384];
  __shared__ __align__(16) unsigned short sWlo[16384];
  __shared__ __align__(16) float sXj[16 * 132];
  __shared__ float sRow[16][8];
  __shared__ float sMir[16];

  int tt = blockIdx.x, ti = 0;
  while (tt >= 16 - ti) { tt -= 16 - ti; ++ti; }
  const int tj = ti + tt;
  const int b = blockIdx.y;
  const int i0 = ti * 16, j0 = tj * 16;
  const int tid = threadIdx.x;

  {  // stage W hi/lo (pre-swizzled copy) + x_j rows
    const uint4* shi = (const uint4*)gWhi;
    const uint4* slo = (const uint4*)gWlo;
    uint4* dhi = (uint4*)sWhi;
    uint4* dlo = (uint4*)sWlo;
#pragma unroll
    for (int r = 0; r < 4; ++r) {
      dhi[tid + 512 * r] = shi[tid + 512 * r];
      dlo[tid + 512 * r] = slo[tid + 512 * r];
    }
    const float4* xsrc = (const float4*)(x + ((size_t)(b * 256 + j0)) * 128);
    *(float4*)&sXj[(tid >> 5) * 132 + (tid & 31) * 4] = xsrc[tid];
  }
  __syncthreads();

  const int lane = tid & 63;
  const int w = tid >> 6;  // 0..7
  const int quad = lane >> 4;
  const int col = lane & 15;
  const int swz = (col & 7) << 3;

  float vw[8];
  f32x4 acc[2][8];
#pragma unroll
  for (int et = 0; et < 8; ++et) {
    float bi = apb[col + 16 * et];
    vw[et] = av[col + 16 * et];
#pragma unroll
    for (int mt = 0; mt < 2; ++mt) acc[mt][et] = (f32x4){bi, bi, bi, bi};
  }

  const float* xib = x + ((size_t)(b * 256 + i0 + 2 * w)) * 128;

#pragma unroll
  for (int kstep = 0; kstep < 4; ++kstep) {
    const int k0 = kstep * 32 + quad * 8;
    float4 xj0 = *(const float4*)&sXj[col * 132 + k0];
    float4 xj1 = *(const float4*)&sXj[col * 132 + k0 + 4];
    s16x8 Ah[2], Al[2];
#pragma unroll
    for (int mt = 0; mt < 2; ++mt) {
      const float* xip = xib + mt * 128 + k0;
      float4 xi0 = *(const float4*)xip;
      float4 xi1 = *(const float4*)(xip + 4);
      float pv[8];
      pv[0] = xi0.x * xj0.x; pv[1] = xi0.y * xj0.y;
      pv[2] = xi0.z * xj0.z; pv[3] = xi0.w * xj0.w;
      pv[4] = xi1.x * xj1.x; pv[5] = xi1.y * xj1.y;
      pv[6] = xi1.z * xj1.z; pv[7] = xi1.w * xj1.w;
      uint4 hp, lp;
      unsigned* hq = (unsigned*)&hp;
      unsigned* lq = (unsigned*)&lp;
#pragma unroll
      for (int p = 0; p < 4; ++p) {
        unsigned u0 = __float_as_uint(pv[2 * p]);
        unsigned u1 = __float_as_uint(pv[2 * p + 1]);
        hq[p] = __builtin_amdgcn_perm(u1, u0, 0x07060302);
        float h0 = __uint_as_float(u0 & 0xffff0000u);
        float h1 = __uint_as_float(u1 & 0xffff0000u);
        unsigned v0 = __float_as_uint(pv[2 * p] - h0) + 0x8000u;
        unsigned v1 = __float_as_uint(pv[2 * p + 1] - h1) + 0x8000u;
        lq[p] = __builtin_amdgcn_perm(v1, v0, 0x07060302);
      }
      Ah[mt] = *(s16x8*)&hp;
      Al[mt] = *(s16x8*)&lp;
    }
#pragma unroll
    for (int et = 0; et < 8; ++et) {
      const int addr = (col + 16 * et) * 128 + (k0 ^ swz);
      s16x8 bh = *(const s16x8*)&sWhi[addr];
      s16x8 bl = *(const s16x8*)&sWlo[addr];
#pragma unroll
      for (int mt = 0; mt < 2; ++mt) {
        acc[mt][et] = __builtin_amdgcn_mfma_f32_16x16x32_bf16(Ah[mt], bh, acc[mt][et], 0, 0, 0);
        acc[mt][et] = __builtin_amdgcn_mfma_f32_16x16x32_bf16(Al[mt], bh, acc[mt][et], 0, 0, 0);
        acc[mt][et] = __builtin_amdgcn_mfma_f32_16x16x32_bf16(Ah[mt], bl, acc[mt][et], 0, 0, 0);
      }
    }
  }

  // epilogue: logit -> E = exp(logit) (no max-sub; |logit|<~8 so safe)
  float E[2];
#pragma unroll
  for (int mt = 0; mt < 2; ++mt) {
    float ls[4] = {0.f, 0.f, 0.f, 0.f};
#pragma unroll
    for (int et = 0; et < 8; ++et) {
#pragma unroll
      for (int r = 0; r < 4; ++r) {
        float e2 = __builtin_amdgcn_exp2f(acc[mt][et][r] * C2L2E);
        float t = 1.0f - 2.0f * __builtin_amdgcn_rcpf(e2 + 1.0f);
        ls[r] += t * vw[et];
      }
    }
#pragma unroll
    for (int m = 1; m < 16; m <<= 1) {
      ls[0] += __shfl_xor(ls[0], m);
      ls[1] += __shfl_xor(ls[1], m);
      ls[2] += __shfl_xor(ls[2], m);
      ls[3] += __shfl_xor(ls[3], m);
    }
    float fl = (col == 0) ? ls[0] : (col == 1) ? ls[1] : (col == 2) ? ls[2] : ls[3];
    E[mt] = __builtin_amdgcn_exp2f(fl * L2E);
  }

  if (col < 4) {  // primary tile write (E for rows j in tj-tile, cols i in ti)
    const int j = j0 + quad * 4 + col;
    float2 val = {E[0], E[1]};
    *(float2*)&Lg[((size_t)(b * 256 + j)) * 256 + i0 + 2 * w] = val;
    sRow[quad * 4 + col][w] = E[0] + E[1];
  }

  if (ti != tj) {  // mirror write + mirror row sums
    if (col < 4) {
      const int j = j0 + quad * 4 + col;
#pragma unroll
      for (int mt = 0; mt < 2; ++mt)
        Lg[((size_t)(b * 256 + i0 + 2 * w + mt)) * 256 + j] = E[mt];
    }
#pragma unroll
    for (int mt = 0; mt < 2; ++mt) {
      float v = (col < 4) ? E[mt] : 0.f;
#pragma unroll
      for (int m = 1; m < 64; m <<= 1) v += __shfl_xor(v, m);
      if (lane == 0) sMir[2 * w + mt] = v;
    }
  }
  __syncthreads();
  if (tid < 16) {
    float rs = sRow[tid][0];
#pragma unroll
    for (int q = 1; q < 8; ++q) rs += sRow[tid][q];
    atomicAdd(&S[b * 256 + j0 + tid], rs);
    if (ti != tj) atomicAdd(&S[b * 256 + i0 + tid], sMir[tid]);
  }
}

// ---------------- KB: agg (att=E/S) + h (fp64) + pool scores ----------------
// r6 restructure: (1) 1/S scale folded into the satt store (same multiplies,
// one pass fewer); (2) x staged in 32-row chunks, DOUBLE-BUFFERED with T14
// issue-early/write-late -> 1 barrier per chunk (8 total vs 32). Accumulation
// order over j unchanged (0..255 ascending) -> bit-identical results.
__global__ __launch_bounds__(256) void kB_aggh(
    const float* __restrict__ Lg, const float* __restrict__ S,
    const float* __restrict__ x,
    const float* __restrict__ pwa, const float* __restrict__ pwoa,
    const float* __restrict__ pwab, const float* __restrict__ pwob,
    const float* __restrict__ gam, const float* __restrict__ bet,
    const float* __restrict__ mea, const float* __restrict__ varr,
    const float* __restrict__ plw, const float* __restrict__ plb,
    float* __restrict__ h, float* __restrict__ scores) {
  const int b = blockIdx.y, i0 = blockIdx.x * 8;
  const int tid = threadIdx.x;
  const int il = tid >> 5, dl = tid & 31;  // 8 i x 32 d-chunks
  __shared__ float sInv[256];
  __shared__ float satt[8][256];           // scaled att rows for 8 i's
  __shared__ __align__(16) float sxj[2][32 * 128];  // x chunk double-buffer
  __shared__ float sa[1024];
  __shared__ float sxi[1024];
  __shared__ double sScD[8][32];

  const float4* xb = (const float4*)(x + ((size_t)b * 256) * 128);

  sInv[tid] = 1.0f / S[b * 256 + tid];
  ((float4*)sxi)[tid] = ((const float4*)(x + ((size_t)(b * 256 + i0)) * 128))[tid];
  // issue Lg row loads + chunk-0 stage before the barrier (independent)
  const float4* lsrc = (const float4*)(Lg + ((size_t)(b * 256 + i0)) * 256);
  float4 l0 = lsrc[tid];
  float4 l1 = lsrc[tid + 256];
#pragma unroll
  for (int r = 0; r < 4; ++r)
    ((float4*)sxj[0])[tid + 256 * r] = xb[tid + 256 * r];
  __syncthreads();  // sInv ready
  {  // att[i][j] = Lg[i][j] * (1/S[j]); j = (4*tid+q) & 255 for both halves
    const int j0q = (tid * 4) & 255;
    float s0 = sInv[j0q], s1 = sInv[j0q + 1], s2 = sInv[j0q + 2], s3 = sInv[j0q + 3];
    l0.x *= s0; l0.y *= s1; l0.z *= s2; l0.w *= s3;
    l1.x *= s0; l1.y *= s1; l1.z *= s2; l1.w *= s3;
    ((float4*)satt)[tid] = l0;
    ((float4*)satt)[tid + 256] = l1;
  }
  __syncthreads();  // satt + chunk 0 ready

  float acc[4] = {0.f, 0.f, 0.f, 0.f};
  for (int c = 0; c < 8; ++c) {
    const int cb = c & 1;
    float4 p0, p1, p2, p3;
    if (c < 7) {  // T14 issue-early: next 32-row chunk global->reg
      const float4* src = xb + (c + 1) * 1024;
      p0 = src[tid]; p1 = src[tid + 256]; p2 = src[tid + 512]; p3 = src[tid + 768];
    }
#pragma unroll
    for (int jl = 0; jl < 32; ++jl) {
      float a = satt[il][c * 32 + jl];
      float4 xv = *(const float4*)&sxj[cb][jl * 128 + dl * 4];
      acc[0] += a * xv.x; acc[1] += a * xv.y;
      acc[2] += a * xv.z; acc[3] += a * xv.w;
    }
    if (c < 7) {  // write-late into the other buffer, single barrier
      float4* dst = (float4*)sxj[cb ^ 1];
      dst[tid] = p0; dst[tid + 256] = p1; dst[tid + 512] = p2; dst[tid + 768] = p3;
      __syncthreads();
    }
  }

  *(float4*)&sa[il * 128 + dl * 4] = *(float4*)acc;
  __syncthreads();

  double z[4] = {0, 0, 0, 0};
#pragma unroll 8
  for (int k = 0; k < 128; ++k) {
    double a = (double)sa[il * 128 + k];
    float4 wv = *(const float4*)(pwa + k * 128 + dl * 4);
    z[0] += a * (double)wv.x; z[1] += a * (double)wv.y;
    z[2] += a * (double)wv.z; z[3] += a * (double)wv.w;
  }
#pragma unroll 8
  for (int k = 0; k < 128; ++k) {
    double a = (double)sxi[il * 128 + k];
    float4 wv = *(const float4*)(pwoa + k * 128 + dl * 4);
    z[0] += a * (double)wv.x; z[1] += a * (double)wv.y;
    z[2] += a * (double)wv.z; z[3] += a * (double)wv.w;
  }
  float o[4];
#pragma unroll
  for (int q = 0; q < 4; ++q) {
    int d = dl * 4 + q;
    double hv = z[q] + (double)pwab[d] + (double)pwob[d];
    double bn = (hv - (double)mea[d]) * (1.0 / sqrt((double)varr[d] + 1e-5)) *
                    (double)gam[d] +
                (double)bet[d];
    float bf = (float)bn;
    o[q] = bf > 0.f ? 1.0507009873554805f * bf
                    : 1.7580993408473766f *
                          (__builtin_amdgcn_exp2f(bf * L2E) - 1.0f);
  }
  *(float4*)(h + ((size_t)(b * 256 + i0 + il)) * 128 + dl * 4) = *(float4*)o;

  // pool score partials (fp64, fixed reduction order -> deterministic)
  sScD[il][dl] = (double)o[0] * (double)plw[dl * 4] +
                 (double)o[1] * (double)plw[dl * 4 + 1] +
                 (double)o[2] * (double)plw[dl * 4 + 2] +
                 (double)o[3] * (double)plw[dl * 4 + 3];
  __syncthreads();
  if (tid < 8) {
    double zz = (double)plb[0];
    for (int c = 0; c < 32; ++c) zz += sScD[tid][c];
    scores[b * 256 + i0 + tid] = (float)(1.0 / (1.0 + exp(-zz)));
  }
}

// ---------------- KC: stable top-128 rank + gather h*score ------------------
// 4 blocks per batch: ranks recomputed per block (cheap, deterministic),
// each block gathers a 32-row quarter -> 4x CU parallelism.
__global__ __launch_bounds__(1024) void kC_topk(const float* __restrict__ h,
                                                const float* __restrict__ scores,
                                                float* __restrict__ out) {
  const int bq = blockIdx.x;
  const int b = bq >> 2, qp = bq & 3;
  const int tid = threadIdx.x;
  const int t = tid >> 2, c = tid & 3;
  __shared__ float sc[256];
  __shared__ int ipart[256][4];
  __shared__ int sel[128];

  if (c == 0) sc[t] = scores[b * 256 + t];
  __syncthreads();
  {
    const float st = sc[t];
    int r = 0;
    for (int m = c * 64; m < c * 64 + 64; ++m) {
      float sm = sc[m];
      r += (sm > st) || (sm == st && m < t);  // stable descending
    }
    ipart[t][c] = r;
  }
  __syncthreads();
  if (c == 0) {
    int rank = ipart[t][0] + ipart[t][1] + ipart[t][2] + ipart[t][3];
    if (rank < 128) sel[rank] = t;
  }
  __syncthreads();
  const float4* h4 = (const float4*)(h + (size_t)b * 256 * 128);
  float4* o4 = (float4*)(out + (size_t)b * 128 * 128);
  const int row = qp * 32 + (tid >> 5);
  const int q = tid & 31;
  int src = sel[row];
  float ss = sc[src];
  float4 hv = h4[src * 32 + q];
  float4 ov;
  ov.x = hv.x * ss; ov.y = hv.y * ss; ov.z = hv.z * ss; ov.w = hv.w * ss;
  o4[row * 32 + q] = ov;
}

extern "C" void kernel_launch(void* const* d_in, const int* in_sizes, int n_in,
                              void* d_out, int out_size, void* d_ws, size_t ws_size,
                              hipStream_t stream) {
  const float* x    = (const float*)d_in[0];
  const float* apw  = (const float*)d_in[1];
  const float* apb  = (const float*)d_in[2];
  const float* av   = (const float*)d_in[3];
  const float* pwa  = (const float*)d_in[4];
  const float* pwab = (const float*)d_in[5];
  const float* pwoa = (const float*)d_in[6];
  const float* pwob = (const float*)d_in[7];
  const float* gam  = (const float*)d_in[8];
  const float* bet  = (const float*)d_in[9];
  const float* mea  = (const float*)d_in[10];
  const float* varr = (const float*)d_in[11];
  const float* plw  = (const float*)d_in[12];
  const float* plb  = (const float*)d_in[13];
  float* out = (float*)d_out;

  // ws: gWhi 32K | gWlo 32K | S 16K | Lg 4M | h 2M | scores 16K
  unsigned short* gWhi = (unsigned short*)d_ws;
  unsigned short* gWlo = gWhi + 16384;
  float* S  = (float*)((char*)d_ws + 65536);
  float* Lg = (float*)((char*)d_ws + 81920);
  float* hb = Lg + (size_t)16 * 256 * 256;
  float* sco = hb + (size_t)16 * 256 * 128;

  k0_prep<<<80, 256, 0, stream>>>(apw, gWhi, gWlo, S);
  kA_logits<<<dim3(136, 16), 512, 0, stream>>>(x, gWhi, gWlo, apb, av, Lg, S);
  kB_aggh<<<dim3(32, 16), 256, 0, stream>>>(Lg, S, x, pwa, pwoa, pwab, pwob,
                                            gam, bet, mea, varr, plw, plb, hb, sco);
  kC_topk<<<64, 1024, 0, stream>>>(hb, sco, out);
}